// Round 2
// baseline (880.703 us; speedup 1.0000x reference)
//
#include <hip/hip_runtime.h>
#include <hip/hip_bf16.h>

typedef __attribute__((ext_vector_type(8))) unsigned short u16x8;
typedef __attribute__((ext_vector_type(4))) unsigned short u16x4;
typedef __attribute__((ext_vector_type(8))) __bf16 bf16x8;
typedef __attribute__((ext_vector_type(4))) float f32x4;

__device__ __forceinline__ unsigned short f2bf(float f) {
  unsigned u = __float_as_uint(f);
  return (unsigned short)((u + 0x7fffu + ((u >> 16) & 1u)) >> 16);  // RNE
}

// swizzled byte offset into a [16 edges][<=128 feats] bf16 buffer, row stride 256B.
// 16B chunks within a row are XOR-permuted by (edge&7) to avoid bank conflicts.
__device__ __forceinline__ int swz(int edge, int feat) {
  return edge * 256 + (((feat >> 3) ^ (edge & 7)) << 4) + (feat & 7) * 2;
}

// ---------------- prep: transpose weights to bf16 [n][k] ----------------
__global__ void prep_weights(const float* __restrict__ W1, const float* __restrict__ W2,
                             const float* __restrict__ W3, const float* __restrict__ W4,
                             unsigned short* __restrict__ wt) {
  int i = blockIdx.x * 256 + threadIdx.x;
  if (i >= 22528) return;
  float v;
  if (i < 4096)       { int n = i >> 6, k = i & 63;                 v = W1[k * 64 + n]; }
  else if (i < 12288) { int j = i - 4096;  int n = j >> 6, k = j & 63;   v = W2[k * 128 + n]; }
  else if (i < 20480) { int j = i - 12288; int n = j >> 7, k = j & 127;  v = W3[k * 64 + n]; }
  else                { int j = i - 20480; int n = j >> 6, k = j & 63;   v = W4[k * 32 + n]; }
  wt[i] = f2bf(v);
}

// ---------------- one MLP layer: dst = relu(W^T srcH + b), all per-wave ----------------
template <int MT, int KS>
__device__ __forceinline__ void mlp_layer(const unsigned char* src, unsigned char* dst,
                                          const u16x8 (&wf)[MT][KS],
                                          const float* __restrict__ biasL, int lane) {
  const int edge = lane & 15, g = lane >> 4;
  asm volatile("s_waitcnt lgkmcnt(0)" ::: "memory");   // prior LDS writes visible wave-wide
  u16x8 bfrag[KS];
#pragma unroll
  for (int ks = 0; ks < KS; ++ks)
    bfrag[ks] = *(const u16x8*)(src + swz(edge, ks * 32 + g * 8));
#pragma unroll
  for (int mt = 0; mt < MT; ++mt) {
    const float4 bv = *(const float4*)(biasL + mt * 16 + g * 4);
    f32x4 acc = {bv.x, bv.y, bv.z, bv.w};
    __builtin_amdgcn_s_setprio(1);
#pragma unroll
    for (int ks = 0; ks < KS; ++ks)
      acc = __builtin_amdgcn_mfma_f32_16x16x32_bf16(
          __builtin_bit_cast(bf16x8, wf[mt][ks]), __builtin_bit_cast(bf16x8, bfrag[ks]),
          acc, 0, 0, 0);
    __builtin_amdgcn_s_setprio(0);
    const int fb = mt * 16 + g * 4;
    u16x4 q;
    q[0] = f2bf(fmaxf(acc[0], 0.f));
    q[1] = f2bf(fmaxf(acc[1], 0.f));
    q[2] = f2bf(fmaxf(acc[2], 0.f));
    q[3] = f2bf(fmaxf(acc[3], 0.f));
    *(u16x4*)(dst + swz(edge, fb)) = q;
  }
}

// prefetch one tile's gather into registers
__device__ __forceinline__ void load_tile(int ebase, int E, const int* __restrict__ ei,
                                          const float* __restrict__ x, const float* __restrict__ ea,
                                          int lane, float4& xa, float4& xb, float4& ya, float4& yb,
                                          int& dstA) {
  const int el = ebase + (lane >> 2);
  const int part = lane & 3;
  xa = make_float4(0.f, 0.f, 0.f, 0.f); xb = xa; ya = xa; yb = xa;
  if (el < E) {
    const int dn = ei[E + el];
    const float4* xp = (const float4*)(x + (size_t)dn * 32 + part * 8);
    xa = xp[0]; xb = xp[1];
    const float4* ep = (const float4*)(ea + (size_t)el * 32 + part * 8);
    ya = ep[0]; yb = ep[1];
  }
  const int eA = ebase + (lane & 15);
  dstA = (eA < E) ? ei[E + eA] : -1;
}

// ---------------- main: gather + MLP + atomic scatter ----------------
__global__ __launch_bounds__(256, 4)
void gnn_main(const float* __restrict__ x, const int* __restrict__ ei,
              const float* __restrict__ ea, const unsigned short* __restrict__ wt,
              const float* __restrict__ b1, const float* __restrict__ b2,
              const float* __restrict__ b3, const float* __restrict__ b4,
              float* __restrict__ out, float* __restrict__ cnt, int E, int numTiles) {
  __shared__ __align__(16) unsigned char lds[4 * 8192 + 288 * 4];
  float* biasLds = (float*)(lds + 4 * 8192);
  for (int i = threadIdx.x; i < 288; i += 256) {
    float v;
    if (i < 64) v = b1[i];
    else if (i < 192) v = b2[i - 64];
    else if (i < 256) v = b3[i - 192];
    else v = b4[i - 256];
    biasLds[i] = v;
  }
  __syncthreads();

  const int lane = threadIdx.x & 63, wid = threadIdx.x >> 6;
  const int edge = lane & 15, g = lane >> 4;
  unsigned char* buf0 = lds + wid * 8192;
  unsigned char* buf1 = buf0 + 4096;

  const unsigned short* w1t = wt;
  const unsigned short* w2t = wt + 4096;
  const unsigned short* w3t = wt + 12288;
  const unsigned short* w4t = wt + 20480;
  u16x8 wf1[4][2], wf2[8][2], wf3[4][4], wf4[2][2];
#pragma unroll
  for (int mt = 0; mt < 4; ++mt)
#pragma unroll
    for (int ks = 0; ks < 2; ++ks)
      wf1[mt][ks] = *(const u16x8*)(w1t + (mt * 16 + edge) * 64 + ks * 32 + g * 8);
#pragma unroll
  for (int mt = 0; mt < 8; ++mt)
#pragma unroll
    for (int ks = 0; ks < 2; ++ks)
      wf2[mt][ks] = *(const u16x8*)(w2t + (mt * 16 + edge) * 64 + ks * 32 + g * 8);
#pragma unroll
  for (int mt = 0; mt < 4; ++mt)
#pragma unroll
    for (int ks = 0; ks < 4; ++ks)
      wf3[mt][ks] = *(const u16x8*)(w3t + (mt * 16 + edge) * 128 + ks * 32 + g * 8);
#pragma unroll
  for (int mt = 0; mt < 2; ++mt)
#pragma unroll
    for (int ks = 0; ks < 2; ++ks)
      wf4[mt][ks] = *(const u16x8*)(w4t + (mt * 16 + edge) * 64 + ks * 32 + g * 8);

  const int wgl = blockIdx.x * 4 + wid;
  const int wstride = gridDim.x * 4;

  float4 xa, xb, ya, yb; int dstA;
  if (wgl < numTiles) load_tile(wgl * 16, E, ei, x, ea, lane, xa, xb, ya, yb, dstA);

  for (int tile = wgl; tile < numTiles; tile += wstride) {
    // ---- stage current tile H0 = concat(x[dst], edge_attr) as bf16 [16][64] ----
    u16x8 hx, he;
    hx[0]=f2bf(xa.x); hx[1]=f2bf(xa.y); hx[2]=f2bf(xa.z); hx[3]=f2bf(xa.w);
    hx[4]=f2bf(xb.x); hx[5]=f2bf(xb.y); hx[6]=f2bf(xb.z); hx[7]=f2bf(xb.w);
    he[0]=f2bf(ya.x); he[1]=f2bf(ya.y); he[2]=f2bf(ya.z); he[3]=f2bf(ya.w);
    he[4]=f2bf(yb.x); he[5]=f2bf(yb.y); he[6]=f2bf(yb.z); he[7]=f2bf(yb.w);
    const int e2 = lane >> 2, part = lane & 3;
    *(u16x8*)(buf0 + swz(e2, part * 8)) = hx;
    *(u16x8*)(buf0 + swz(e2, 32 + part * 8)) = he;

    const int curDst = dstA;

    // ---- issue next tile's gather now; it drains under the MFMA chain ----
    const int nt = tile + wstride;
    float4 nxa, nxb, nya, nyb; int ndst = -1;
    if (nt < numTiles) load_tile(nt * 16, E, ei, x, ea, lane, nxa, nxb, nya, nyb, ndst);
    else { nxa = make_float4(0,0,0,0); nxb = nxa; nya = nxa; nyb = nxa; }

    mlp_layer<4, 2>(buf0, buf1, wf1, biasLds + 0,   lane);
    mlp_layer<8, 2>(buf1, buf0, wf2, biasLds + 64,  lane);
    mlp_layer<4, 4>(buf0, buf1, wf3, biasLds + 192, lane);

    // ---- layer 4 + atomic mean-scatter ----
    asm volatile("s_waitcnt lgkmcnt(0)" ::: "memory");
    u16x8 bf4[2];
#pragma unroll
    for (int ks = 0; ks < 2; ++ks)
      bf4[ks] = *(const u16x8*)(buf1 + swz(edge, ks * 32 + g * 8));
#pragma unroll
    for (int mt = 0; mt < 2; ++mt) {
      const float4 bv = *(const float4*)(biasLds + 256 + mt * 16 + g * 4);
      f32x4 acc = {bv.x, bv.y, bv.z, bv.w};
      __builtin_amdgcn_s_setprio(1);
#pragma unroll
      for (int ks = 0; ks < 2; ++ks)
        acc = __builtin_amdgcn_mfma_f32_16x16x32_bf16(
            __builtin_bit_cast(bf16x8, wf4[mt][ks]), __builtin_bit_cast(bf16x8, bf4[ks]),
            acc, 0, 0, 0);
      __builtin_amdgcn_s_setprio(0);
      if (curDst >= 0) {
        float* op = out + (size_t)curDst * 32 + mt * 16 + g * 4;
#pragma unroll
        for (int r = 0; r < 4; ++r) unsafeAtomicAdd(op + r, fmaxf(acc[r], 0.f));
      }
    }
    if (lane < 16 && curDst >= 0) unsafeAtomicAdd(cnt + curDst, 1.0f);

    xa = nxa; xb = nxb; ya = nya; yb = nyb; dstA = ndst;
  }
}

__global__ void div_kernel(float* __restrict__ out, const float* __restrict__ cnt, int total) {
  int i = blockIdx.x * 256 + threadIdx.x;
  if (i < total) out[i] = out[i] / fmaxf(cnt[i >> 5], 1.0f);
}

extern "C" void kernel_launch(void* const* d_in, const int* in_sizes, int n_in,
                              void* d_out, int out_size, void* d_ws, size_t ws_size,
                              hipStream_t stream) {
  const float* x  = (const float*)d_in[0];
  const int*   ei = (const int*)d_in[1];
  const float* ea = (const float*)d_in[2];
  const float* W1 = (const float*)d_in[3];
  const float* b1 = (const float*)d_in[4];
  const float* W2 = (const float*)d_in[5];
  const float* b2 = (const float*)d_in[6];
  const float* W3 = (const float*)d_in[7];
  const float* b3 = (const float*)d_in[8];
  const float* W4 = (const float*)d_in[9];
  const float* b4 = (const float*)d_in[10];
  const int N = in_sizes[0] / 32;
  const int E = in_sizes[1] / 2;
  float* out = (float*)d_out;
  float* cnt = (float*)d_ws;
  unsigned short* wt = (unsigned short*)((char*)d_ws + (((size_t)N * 4 + 255) / 256) * 256);

  hipMemsetAsync(d_out, 0, (size_t)out_size * sizeof(float), stream);
  hipMemsetAsync(cnt, 0, (size_t)N * sizeof(float), stream);
  prep_weights<<<(22528 + 255) / 256, 256, 0, stream>>>(W1, W2, W3, W4, wt);
  const int numTiles = (E + 15) / 16;
  gnn_main<<<1024, 256, 0, stream>>>(x, ei, ea, wt, b1, b2, b3, b4, out, cnt, E, numTiles);
  const int total = N * 32;
  div_kernel<<<(total + 255) / 256, 256, 0, stream>>>(out, cnt, total);
}

// Round 3
// 764.068 us; speedup vs baseline: 1.1527x; 1.1527x over previous
//
#include <hip/hip_runtime.h>
#include <hip/hip_bf16.h>

typedef __attribute__((ext_vector_type(8))) unsigned short u16x8;
typedef __attribute__((ext_vector_type(4))) unsigned short u16x4;
typedef __attribute__((ext_vector_type(8))) __bf16 bf16x8;
typedef __attribute__((ext_vector_type(4))) float f32x4;

__device__ __forceinline__ unsigned short f2bf(float f) {
  unsigned u = __float_as_uint(f);
  return (unsigned short)((u + 0x7fffu + ((u >> 16) & 1u)) >> 16);  // RNE
}

// swizzled byte offset into a [16 rows][stride bytes] bf16 buffer.
// 16B chunks within a row are XOR-permuted by (row&7) -> bank-conflict-free
// for both the b128 fragment reads (16 rows x 4 chunks) and the b64 writes.
__device__ __forceinline__ int aswz(int row, int feat, int stride) {
  return row * stride + (((feat >> 3) ^ (row & 7)) << 4) + (feat & 7) * 2;
}

// ---- prep: weights -> bf16, transposed to [n][k], PRE-SWIZZLED 16B chunks ----
__global__ void prep_weights(const float* __restrict__ W1, const float* __restrict__ W2,
                             const float* __restrict__ W3, const float* __restrict__ W4,
                             unsigned short* __restrict__ wt) {
  int i = blockIdx.x * 256 + threadIdx.x;
  if (i >= 22528) return;
  float v; int n, k, K, base;
  if (i < 4096)       { n = i >> 6, k = i & 63;  K = 64;  base = 0;     v = W1[k * 64 + n]; }
  else if (i < 12288) { int j = i - 4096;  n = j >> 6, k = j & 63;  K = 64;  base = 4096;  v = W2[k * 128 + n]; }
  else if (i < 20480) { int j = i - 12288; n = j >> 7, k = j & 127; K = 128; base = 12288; v = W3[k * 64 + n]; }
  else                { int j = i - 20480; n = j >> 6, k = j & 63;  K = 64;  base = 20480; v = W4[k * 32 + n]; }
  int o = base + n * K + ((((k >> 3) ^ (n & 7)) << 3) + (k & 7));
  wt[o] = f2bf(v);
}

// ---- one MLP layer: dst = relu(W^T srcH + b); weights read from LDS ----
template <int MT, int KS, int SS, int DS>
__device__ __forceinline__ void mlp_layer(const unsigned char* src, unsigned char* dst,
                                          const unsigned char* wl, const float* biasL, int lane) {
  const int edge = lane & 15, g = lane >> 4;
  asm volatile("s_waitcnt lgkmcnt(0)" ::: "memory");   // prior LDS writes visible wave-wide
  u16x8 bfrag[KS];
#pragma unroll
  for (int ks = 0; ks < KS; ++ks)
    bfrag[ks] = *(const u16x8*)(src + aswz(edge, ks * 32 + g * 8, SS));
#pragma unroll
  for (int mt = 0; mt < MT; ++mt) {
    const int n = mt * 16 + edge;
    u16x8 af[KS];
#pragma unroll
    for (int ks = 0; ks < KS; ++ks)
      af[ks] = *(const u16x8*)(wl + n * (KS * 64) + (((ks * 4 + g) ^ (edge & 7)) << 4));
    const float4 bv = *(const float4*)(biasL + mt * 16 + g * 4);
    f32x4 acc = {bv.x, bv.y, bv.z, bv.w};
    __builtin_amdgcn_s_setprio(1);
#pragma unroll
    for (int ks = 0; ks < KS; ++ks)
      acc = __builtin_amdgcn_mfma_f32_16x16x32_bf16(
          __builtin_bit_cast(bf16x8, af[ks]), __builtin_bit_cast(bf16x8, bfrag[ks]),
          acc, 0, 0, 0);
    __builtin_amdgcn_s_setprio(0);
    const int fb = mt * 16 + g * 4;
    u16x4 q;
    q[0] = f2bf(fmaxf(acc[0], 0.f));
    q[1] = f2bf(fmaxf(acc[1], 0.f));
    q[2] = f2bf(fmaxf(acc[2], 0.f));
    q[3] = f2bf(fmaxf(acc[3], 0.f));
    *(u16x4*)(dst + aswz(edge, fb, DS)) = q;
  }
}

// prefetch one tile's gather into registers
__device__ __forceinline__ void load_tile(int ebase, int E, const int* __restrict__ ei,
                                          const float* __restrict__ x, const float* __restrict__ ea,
                                          int lane, float4& xa, float4& xb, float4& ya, float4& yb,
                                          int& dstA) {
  const int el = ebase + (lane >> 2);
  const int part = lane & 3;
  xa = make_float4(0.f, 0.f, 0.f, 0.f); xb = xa; ya = xa; yb = xa;
  if (el < E) {
    const int dn = ei[E + el];
    const float4* xp = (const float4*)(x + (size_t)dn * 32 + part * 8);
    xa = xp[0]; xb = xp[1];
    const float4* ep = (const float4*)(ea + (size_t)el * 32 + part * 8);
    ya = ep[0]; yb = ep[1];
  }
  const int eA = ebase + (lane & 15);
  dstA = (eA < E) ? ei[E + eA] : -1;
}

// LDS layout: [weights 45056][bias 1152][16 waves x (buf0 4096 + buf1 2048)]
#define WLDS_BYTES 45056
#define BIAS_OFF   45056
#define ACT_OFF    46208

__global__ __launch_bounds__(1024, 4)
void gnn_main(const float* __restrict__ x, const int* __restrict__ ei,
              const float* __restrict__ ea, const unsigned short* __restrict__ wt,
              const float* __restrict__ b1, const float* __restrict__ b2,
              const float* __restrict__ b3, const float* __restrict__ b4,
              float* __restrict__ out, float* __restrict__ cnt, int E, int numTiles) {
  __shared__ __align__(16) unsigned char lds[ACT_OFF + 16 * 6144];
  // stage weights (straight copy: global buffer is already swizzled)
  {
    const u16x8* gw = (const u16x8*)wt;
    u16x8* lw = (u16x8*)lds;
    for (int i = threadIdx.x; i < 2816; i += 1024) lw[i] = gw[i];
    float* biasLds = (float*)(lds + BIAS_OFF);
    for (int i = threadIdx.x; i < 288; i += 1024) {
      float v;
      if (i < 64) v = b1[i];
      else if (i < 192) v = b2[i - 64];
      else if (i < 256) v = b3[i - 192];
      else v = b4[i - 256];
      biasLds[i] = v;
    }
  }
  __syncthreads();

  const int lane = threadIdx.x & 63, wid = threadIdx.x >> 6;
  const int edge = lane & 15, g = lane >> 4;
  const float* biasLds = (const float*)(lds + BIAS_OFF);
  unsigned char* buf0 = lds + ACT_OFF + wid * 6144;          // stride 256, up to 128 feats
  unsigned char* buf1 = buf0 + 4096;                          // stride 128, up to 64 feats
  const unsigned char* wl1 = lds;                             // 64 rows x 128B
  const unsigned char* wl2 = lds + 8192;                      // 128 rows x 128B
  const unsigned char* wl3 = lds + 24576;                     // 64 rows x 256B
  const unsigned char* wl4 = lds + 40960;                     // 32 rows x 128B

  const int wgl = blockIdx.x * 16 + wid;
  const int wstride = gridDim.x * 16;

  float4 xa, xb, ya, yb; int dstA = -1;
  if (wgl < numTiles) load_tile(wgl * 16, E, ei, x, ea, lane, xa, xb, ya, yb, dstA);

  for (int tile = wgl; tile < numTiles; tile += wstride) {
    // ---- stage current tile H0 = concat(x[dst], edge_attr) as bf16 [16][64] ----
    u16x8 hx, he;
    hx[0]=f2bf(xa.x); hx[1]=f2bf(xa.y); hx[2]=f2bf(xa.z); hx[3]=f2bf(xa.w);
    hx[4]=f2bf(xb.x); hx[5]=f2bf(xb.y); hx[6]=f2bf(xb.z); hx[7]=f2bf(xb.w);
    he[0]=f2bf(ya.x); he[1]=f2bf(ya.y); he[2]=f2bf(ya.z); he[3]=f2bf(ya.w);
    he[4]=f2bf(yb.x); he[5]=f2bf(yb.y); he[6]=f2bf(yb.z); he[7]=f2bf(yb.w);
    const int e2 = lane >> 2, part = lane & 3;
    *(u16x8*)(buf0 + aswz(e2, part * 8, 256)) = hx;
    *(u16x8*)(buf0 + aswz(e2, 32 + part * 8, 256)) = he;

    const int curDst = dstA;

    // ---- issue next tile's gather now; it drains under the MFMA chain ----
    const int nt = tile + wstride;
    float4 nxa, nxb, nya, nyb; int ndst = -1;
    if (nt < numTiles) load_tile(nt * 16, E, ei, x, ea, lane, nxa, nxb, nya, nyb, ndst);
    else { nxa = make_float4(0,0,0,0); nxb = nxa; nya = nxa; nyb = nxa; }

    mlp_layer<4, 2, 256, 128>(buf0, buf1, wl1, biasLds + 0,   lane);   // 64 -> 64
    mlp_layer<8, 2, 128, 256>(buf1, buf0, wl2, biasLds + 64,  lane);   // 64 -> 128
    mlp_layer<4, 4, 256, 128>(buf0, buf1, wl3, biasLds + 192, lane);   // 128 -> 64

    // ---- layer 4 + atomic mean-scatter ----
    asm volatile("s_waitcnt lgkmcnt(0)" ::: "memory");
    u16x8 bf4[2];
#pragma unroll
    for (int ks = 0; ks < 2; ++ks)
      bf4[ks] = *(const u16x8*)(buf1 + aswz(edge, ks * 32 + g * 8, 128));
#pragma unroll
    for (int mt = 0; mt < 2; ++mt) {
      const int n = mt * 16 + edge;
      u16x8 af[2];
#pragma unroll
      for (int ks = 0; ks < 2; ++ks)
        af[ks] = *(const u16x8*)(wl4 + n * 128 + (((ks * 4 + g) ^ (edge & 7)) << 4));
      const float4 bv = *(const float4*)(biasLds + 256 + mt * 16 + g * 4);
      f32x4 acc = {bv.x, bv.y, bv.z, bv.w};
      __builtin_amdgcn_s_setprio(1);
#pragma unroll
      for (int ks = 0; ks < 2; ++ks)
        acc = __builtin_amdgcn_mfma_f32_16x16x32_bf16(
            __builtin_bit_cast(bf16x8, af[ks]), __builtin_bit_cast(bf16x8, bf4[ks]),
            acc, 0, 0, 0);
      __builtin_amdgcn_s_setprio(0);
      if (curDst >= 0) {
        float* op = out + (size_t)curDst * 32 + mt * 16 + g * 4;
#pragma unroll
        for (int r = 0; r < 4; ++r) unsafeAtomicAdd(op + r, fmaxf(acc[r], 0.f));
      }
    }
    if (lane < 16 && curDst >= 0) unsafeAtomicAdd(cnt + curDst, 1.0f);

    xa = nxa; xb = nxb; ya = nya; yb = nyb; dstA = ndst;
  }
}

__global__ void div_kernel(float* __restrict__ out, const float* __restrict__ cnt, int total) {
  int i = blockIdx.x * 256 + threadIdx.x;
  if (i < total) out[i] = out[i] / fmaxf(cnt[i >> 5], 1.0f);
}

extern "C" void kernel_launch(void* const* d_in, const int* in_sizes, int n_in,
                              void* d_out, int out_size, void* d_ws, size_t ws_size,
                              hipStream_t stream) {
  const float* x  = (const float*)d_in[0];
  const int*   ei = (const int*)d_in[1];
  const float* ea = (const float*)d_in[2];
  const float* W1 = (const float*)d_in[3];
  const float* b1 = (const float*)d_in[4];
  const float* W2 = (const float*)d_in[5];
  const float* b2 = (const float*)d_in[6];
  const float* W3 = (const float*)d_in[7];
  const float* b3 = (const float*)d_in[8];
  const float* W4 = (const float*)d_in[9];
  const float* b4 = (const float*)d_in[10];
  const int N = in_sizes[0] / 32;
  const int E = in_sizes[1] / 2;
  float* out = (float*)d_out;
  float* cnt = (float*)d_ws;
  unsigned short* wt = (unsigned short*)((char*)d_ws + (((size_t)N * 4 + 255) / 256) * 256);

  hipMemsetAsync(d_out, 0, (size_t)out_size * sizeof(float), stream);
  hipMemsetAsync(cnt, 0, (size_t)N * sizeof(float), stream);
  prep_weights<<<(22528 + 255) / 256, 256, 0, stream>>>(W1, W2, W3, W4, wt);
  const int numTiles = (E + 15) / 16;
  gnn_main<<<256, 1024, 0, stream>>>(x, ei, ea, wt, b1, b2, b3, b4, out, cnt, E, numTiles);
  const int total = N * 32;
  div_kernel<<<(total + 255) / 256, 256, 0, stream>>>(out, cnt, total);
}

// Round 4
// 420.336 us; speedup vs baseline: 2.0952x; 1.8178x over previous
//
#include <hip/hip_runtime.h>
#include <hip/hip_bf16.h>

typedef __attribute__((ext_vector_type(8))) unsigned short u16x8;
typedef __attribute__((ext_vector_type(4))) unsigned short u16x4;
typedef __attribute__((ext_vector_type(8))) __bf16 bf16x8;
typedef __attribute__((ext_vector_type(4))) float f32x4;

__device__ __forceinline__ unsigned short f2bf(float f) {
  unsigned u = __float_as_uint(f);
  return (unsigned short)((u + 0x7fffu + ((u >> 16) & 1u)) >> 16);  // RNE
}

// swizzled byte offset into a [16 rows][stride bytes] bf16 buffer.
__device__ __forceinline__ int aswz(int row, int feat, int stride) {
  return row * stride + (((feat >> 3) ^ (row & 7)) << 4) + (feat & 7) * 2;
}

// ---- prep: weights -> bf16, transposed to [n][k], PRE-SWIZZLED 16B chunks ----
__global__ void prep_weights(const float* __restrict__ W1, const float* __restrict__ W2,
                             const float* __restrict__ W3, const float* __restrict__ W4,
                             unsigned short* __restrict__ wt) {
  int i = blockIdx.x * 256 + threadIdx.x;
  if (i >= 22528) return;
  float v; int n, k, K, base;
  if (i < 4096)       { n = i >> 6, k = i & 63;  K = 64;  base = 0;     v = W1[k * 64 + n]; }
  else if (i < 12288) { int j = i - 4096;  n = j >> 6, k = j & 63;  K = 64;  base = 4096;  v = W2[k * 128 + n]; }
  else if (i < 20480) { int j = i - 12288; n = j >> 7, k = j & 127; K = 128; base = 12288; v = W3[k * 64 + n]; }
  else                { int j = i - 20480; n = j >> 6, k = j & 63;  K = 64;  base = 20480; v = W4[k * 32 + n]; }
  int o = base + n * K + ((((k >> 3) ^ (n & 7)) << 3) + (k & 7));
  wt[o] = f2bf(v);
}

// ---- CSR build ----
__global__ void hist_kernel(const int* __restrict__ ei, int* __restrict__ histI, int E) {
  int e = blockIdx.x * 256 + threadIdx.x;
  if (e < E) atomicAdd(&histI[ei[E + e]], 1);
}

__global__ void scan_kernel(const int* __restrict__ histI, int* __restrict__ row_start,
                            int N, int E) {
  __shared__ int waveSums[16];
  __shared__ int baseSh;
  if (threadIdx.x == 0) baseSh = 0;
  __syncthreads();
  const int lane = threadIdx.x & 63, w = threadIdx.x >> 6;
  for (int c = 0; c < N; c += 1024) {
    int i = c + threadIdx.x;
    int v = (i < N) ? histI[i] : 0;
    int s = v;
#pragma unroll
    for (int d = 1; d < 64; d <<= 1) {
      int t = __shfl_up(s, d, 64);
      if (lane >= d) s += t;
    }
    if (lane == 63) waveSums[w] = s;
    __syncthreads();
    if (w == 0 && lane < 16) {
      int ws = waveSums[lane];
#pragma unroll
      for (int d = 1; d < 16; d <<= 1) {
        int t = __shfl_up(ws, d, 16);
        if (lane >= d) ws += t;
      }
      waveSums[lane] = ws;
    }
    __syncthreads();
    int waveOff = (w == 0) ? 0 : waveSums[w - 1];
    int base = baseSh;
    if (i < N) row_start[i] = base + waveOff + s - v;
    __syncthreads();
    if (threadIdx.x == 1023) baseSh = base + waveSums[15];
    __syncthreads();
  }
  if (threadIdx.x == 0) row_start[N] = E;
}

__global__ void fill_kernel(const int* __restrict__ ei, const int* __restrict__ row_start,
                            int* __restrict__ wcnt, int* __restrict__ idx_sorted,
                            int* __restrict__ dst_sorted, int E) {
  int e = blockIdx.x * 256 + threadIdx.x;
  if (e >= E) return;
  int d = ei[E + e];
  int slot = atomicAdd(&wcnt[d], 1);
  int p = row_start[d] + slot;
  idx_sorted[p] = e;
  dst_sorted[p] = d;
}

// ---- one MLP layer: dst = relu(W^T srcH + b); weights read from LDS ----
template <int MT, int KS, int SS, int DS>
__device__ __forceinline__ void mlp_layer(const unsigned char* src, unsigned char* dst,
                                          const unsigned char* wl, const float* biasL, int lane) {
  const int edge = lane & 15, g = lane >> 4;
  asm volatile("s_waitcnt lgkmcnt(0)" ::: "memory");
  u16x8 bfrag[KS];
#pragma unroll
  for (int ks = 0; ks < KS; ++ks)
    bfrag[ks] = *(const u16x8*)(src + aswz(edge, ks * 32 + g * 8, SS));
#pragma unroll
  for (int mt = 0; mt < MT; ++mt) {
    const int n = mt * 16 + edge;
    u16x8 af[KS];
#pragma unroll
    for (int ks = 0; ks < KS; ++ks)
      af[ks] = *(const u16x8*)(wl + n * (KS * 64) + (((ks * 4 + g) ^ (edge & 7)) << 4));
    const float4 bv = *(const float4*)(biasL + mt * 16 + g * 4);
    f32x4 acc = {bv.x, bv.y, bv.z, bv.w};
    __builtin_amdgcn_s_setprio(1);
#pragma unroll
    for (int ks = 0; ks < KS; ++ks)
      acc = __builtin_amdgcn_mfma_f32_16x16x32_bf16(
          __builtin_bit_cast(bf16x8, af[ks]), __builtin_bit_cast(bf16x8, bfrag[ks]),
          acc, 0, 0, 0);
    __builtin_amdgcn_s_setprio(0);
    const int fb = mt * 16 + g * 4;
    u16x4 q;
    q[0] = f2bf(fmaxf(acc[0], 0.f));
    q[1] = f2bf(fmaxf(acc[1], 0.f));
    q[2] = f2bf(fmaxf(acc[2], 0.f));
    q[3] = f2bf(fmaxf(acc[3], 0.f));
    *(u16x4*)(dst + aswz(edge, fb, DS)) = q;
  }
}

// prefetch one tile's gather (CSR order) into registers
__device__ __forceinline__ void load_tile(int ebase, int E, const int* __restrict__ idx_sorted,
                                          const int* __restrict__ dst_sorted,
                                          const float* __restrict__ x, const float* __restrict__ ea,
                                          int lane, float4& xa, float4& xb, float4& ya, float4& yb,
                                          int& dstA) {
  const int el = ebase + (lane >> 2);   // CSR position staged by this lane
  const int part = lane & 3;
  xa = make_float4(0.f, 0.f, 0.f, 0.f); xb = xa; ya = xa; yb = xa;
  if (el < E) {
    const int e = idx_sorted[el];
    const int dn = dst_sorted[el];
    const float4* xp = (const float4*)(x + (size_t)dn * 32 + part * 8);
    xa = xp[0]; xb = xp[1];
    const float4* ep = (const float4*)(ea + (size_t)e * 32 + part * 8);
    ya = ep[0]; yb = ep[1];
  }
  const int pos = ebase + (lane & 15);
  dstA = (pos < E) ? dst_sorted[pos] : -1;
}

// LDS layout: [weights 45056][bias 1152][16 waves x (buf0 4096 + buf1 2048)]
#define BIAS_OFF   45056
#define ACT_OFF    46208

__global__ __launch_bounds__(1024, 4)
void gnn_main(const float* __restrict__ x, const int* __restrict__ idx_sorted,
              const int* __restrict__ dst_sorted,
              const float* __restrict__ ea, const unsigned short* __restrict__ wt,
              const float* __restrict__ b1, const float* __restrict__ b2,
              const float* __restrict__ b3, const float* __restrict__ b4,
              float* __restrict__ out, int E, int numTiles) {
  __shared__ __align__(16) unsigned char lds[ACT_OFF + 16 * 6144];
  {
    const u16x8* gw = (const u16x8*)wt;
    u16x8* lw = (u16x8*)lds;
    for (int i = threadIdx.x; i < 2816; i += 1024) lw[i] = gw[i];
    float* biasW = (float*)(lds + BIAS_OFF);
    for (int i = threadIdx.x; i < 288; i += 1024) {
      float v;
      if (i < 64) v = b1[i];
      else if (i < 192) v = b2[i - 64];
      else if (i < 256) v = b3[i - 192];
      else v = b4[i - 256];
      biasW[i] = v;
    }
  }
  __syncthreads();

  const int lane = threadIdx.x & 63, wid = threadIdx.x >> 6;
  const int edge = lane & 15, g = lane >> 4;
  const float* biasLds = (const float*)(lds + BIAS_OFF);
  unsigned char* buf0 = lds + ACT_OFF + wid * 6144;
  unsigned char* buf1 = buf0 + 4096;
  const unsigned char* wl1 = lds;
  const unsigned char* wl2 = lds + 8192;
  const unsigned char* wl3 = lds + 24576;
  const unsigned char* wl4 = lds + 40960;

  const int wgl = blockIdx.x * 16 + wid;
  const int wstride = gridDim.x * 16;

  float4 xa, xb, ya, yb; int dstA = -1;
  if (wgl < numTiles) load_tile(wgl * 16, E, idx_sorted, dst_sorted, x, ea, lane, xa, xb, ya, yb, dstA);

  for (int tile = wgl; tile < numTiles; tile += wstride) {
    // ---- stage current tile H0 = concat(x[dst], edge_attr) as bf16 [16][64] ----
    u16x8 hx, he;
    hx[0]=f2bf(xa.x); hx[1]=f2bf(xa.y); hx[2]=f2bf(xa.z); hx[3]=f2bf(xa.w);
    hx[4]=f2bf(xb.x); hx[5]=f2bf(xb.y); hx[6]=f2bf(xb.z); hx[7]=f2bf(xb.w);
    he[0]=f2bf(ya.x); he[1]=f2bf(ya.y); he[2]=f2bf(ya.z); he[3]=f2bf(ya.w);
    he[4]=f2bf(yb.x); he[5]=f2bf(yb.y); he[6]=f2bf(yb.z); he[7]=f2bf(yb.w);
    const int e2 = lane >> 2, part = lane & 3;
    *(u16x8*)(buf0 + aswz(e2, part * 8, 256)) = hx;
    *(u16x8*)(buf0 + aswz(e2, 32 + part * 8, 256)) = he;

    const int curDst = dstA;

    // ---- issue next tile's gather now; it drains under the MFMA chain ----
    const int nt = tile + wstride;
    float4 nxa, nxb, nya, nyb; int ndst = -1;
    if (nt < numTiles) load_tile(nt * 16, E, idx_sorted, dst_sorted, x, ea, lane, nxa, nxb, nya, nyb, ndst);
    else { nxa = make_float4(0,0,0,0); nxb = nxa; nya = nxa; nyb = nxa; }

    mlp_layer<4, 2, 256, 128>(buf0, buf1, wl1, biasLds + 0,   lane);   // 64 -> 64
    mlp_layer<8, 2, 128, 256>(buf1, buf0, wl2, biasLds + 64,  lane);   // 64 -> 128
    mlp_layer<4, 4, 256, 128>(buf0, buf1, wl3, biasLds + 192, lane);   // 128 -> 64

    // ---- layer 4 + segmented lane-reduce + sparse atomics ----
    asm volatile("s_waitcnt lgkmcnt(0)" ::: "memory");
    u16x8 bf4[2];
#pragma unroll
    for (int ks = 0; ks < 2; ++ks)
      bf4[ks] = *(const u16x8*)(buf1 + aswz(edge, ks * 32 + g * 8, 128));
    float vals[8];
#pragma unroll
    for (int mt = 0; mt < 2; ++mt) {
      const int n = mt * 16 + edge;
      u16x8 af[2];
#pragma unroll
      for (int ks = 0; ks < 2; ++ks)
        af[ks] = *(const u16x8*)(wl4 + n * 128 + (((ks * 4 + g) ^ (edge & 7)) << 4));
      const float4 bv = *(const float4*)(biasLds + 256 + mt * 16 + g * 4);
      f32x4 acc = {bv.x, bv.y, bv.z, bv.w};
      __builtin_amdgcn_s_setprio(1);
#pragma unroll
      for (int ks = 0; ks < 2; ++ks)
        acc = __builtin_amdgcn_mfma_f32_16x16x32_bf16(
            __builtin_bit_cast(bf16x8, af[ks]), __builtin_bit_cast(bf16x8, bf4[ks]),
            acc, 0, 0, 0);
      __builtin_amdgcn_s_setprio(0);
#pragma unroll
      for (int r = 0; r < 4; ++r) vals[mt * 4 + r] = fmaxf(acc[r], 0.f);
    }

    // segmented sum across the 16-edge lane dim (CSR order => equal dsts adjacent)
    const int li = edge;
    const int prev = __shfl_up(curDst, 1, 16);
    const bool is_head = (li == 0) || (prev != curDst);
    const unsigned long long hb = __ballot(is_head);
    const unsigned gm = (unsigned)((hb >> (g * 16)) & 0xFFFFu);
    const unsigned below = gm & ((1u << li) | ((1u << li) - 1u));
    const int dist = li - (31 - __clz(below));
#pragma unroll
    for (int d = 1; d < 16; d <<= 1) {
#pragma unroll
      for (int t = 0; t < 8; ++t) {
        const float tv = __shfl_up(vals[t], d, 16);
        if (dist >= d) vals[t] += tv;
      }
    }
    const bool is_end = (li == 15) || ((gm >> (li + 1)) & 1u);
    if (is_end && curDst >= 0) {
      float* op = out + (size_t)curDst * 32 + g * 4;
#pragma unroll
      for (int t = 0; t < 4; ++t) unsafeAtomicAdd(op + t, vals[t]);
#pragma unroll
      for (int t = 0; t < 4; ++t) unsafeAtomicAdd(op + 16 + t, vals[4 + t]);
    }

    xa = nxa; xb = nxb; ya = nya; yb = nyb; dstA = ndst;
  }
}

__global__ void div_kernel(float* __restrict__ out, const int* __restrict__ histI, int total) {
  int i = blockIdx.x * 256 + threadIdx.x;
  if (i < total) out[i] = out[i] / fmaxf((float)histI[i >> 5], 1.0f);
}

extern "C" void kernel_launch(void* const* d_in, const int* in_sizes, int n_in,
                              void* d_out, int out_size, void* d_ws, size_t ws_size,
                              hipStream_t stream) {
  const float* x  = (const float*)d_in[0];
  const int*   ei = (const int*)d_in[1];
  const float* ea = (const float*)d_in[2];
  const float* W1 = (const float*)d_in[3];
  const float* b1 = (const float*)d_in[4];
  const float* W2 = (const float*)d_in[5];
  const float* b2 = (const float*)d_in[6];
  const float* W3 = (const float*)d_in[7];
  const float* b3 = (const float*)d_in[8];
  const float* W4 = (const float*)d_in[9];
  const float* b4 = (const float*)d_in[10];
  const int N = in_sizes[0] / 32;
  const int E = in_sizes[1] / 2;
  float* out = (float*)d_out;

  char* ws = (char*)d_ws;
  size_t off = 0;
  auto alloc = [&](size_t bytes) { size_t o = off; off += (bytes + 255) & ~(size_t)255; return o; };
  int* histI      = (int*)(ws + alloc((size_t)N * 4));
  int* wcnt       = (int*)(ws + alloc((size_t)N * 4));
  int* row_start  = (int*)(ws + alloc((size_t)(N + 1) * 4));
  int* idx_sorted = (int*)(ws + alloc((size_t)E * 4));
  int* dst_sorted = (int*)(ws + alloc((size_t)E * 4));
  unsigned short* wt = (unsigned short*)(ws + alloc(22528 * 2));

  hipMemsetAsync(d_out, 0, (size_t)out_size * sizeof(float), stream);
  hipMemsetAsync(histI, 0, (size_t)N * 4, stream);
  hipMemsetAsync(wcnt, 0, (size_t)N * 4, stream);

  prep_weights<<<(22528 + 255) / 256, 256, 0, stream>>>(W1, W2, W3, W4, wt);
  hist_kernel<<<(E + 255) / 256, 256, 0, stream>>>(ei, histI, E);
  scan_kernel<<<1, 1024, 0, stream>>>(histI, row_start, N, E);
  fill_kernel<<<(E + 255) / 256, 256, 0, stream>>>(ei, row_start, wcnt, idx_sorted, dst_sorted, E);

  const int numTiles = (E + 15) / 16;
  gnn_main<<<256, 1024, 0, stream>>>(x, idx_sorted, dst_sorted, ea, wt, b1, b2, b3, b4,
                                     out, E, numTiles);
  const int total = N * 32;
  div_kernel<<<(total + 255) / 256, 256, 0, stream>>>(out, histI, total);
}

// Round 5
// 334.116 us; speedup vs baseline: 2.6359x; 1.2581x over previous
//
#include <hip/hip_runtime.h>
#include <hip/hip_bf16.h>

typedef __attribute__((ext_vector_type(8))) unsigned short u16x8;
typedef __attribute__((ext_vector_type(8))) __bf16 bf16x8;
typedef __attribute__((ext_vector_type(4))) float f32x4;

// pack two f32 -> two bf16 (round-half-up): 2 adds + 1 v_perm_b32
__device__ __forceinline__ unsigned pack_bf2(float lo, float hi) {
  unsigned a = __float_as_uint(lo) + 0x8000u;
  unsigned b = __float_as_uint(hi) + 0x8000u;
  return __builtin_amdgcn_perm(b, a, 0x07060302);  // [a.b2,a.b3,b.b2,b.b3]
}

__device__ __forceinline__ unsigned short f2bf(float f) {
  unsigned u = __float_as_uint(f);
  return (unsigned short)((u + 0x7fffu + ((u >> 16) & 1u)) >> 16);  // RNE (prep only)
}

// swizzled byte offset into a [16 rows][stride bytes] bf16 buffer.
__device__ __forceinline__ int aswz(int row, int feat, int stride) {
  return row * stride + (((feat >> 3) ^ (row & 7)) << 4) + (feat & 7) * 2;
}

// ---- prep: weights -> bf16, transposed to [n][k], PRE-SWIZZLED 16B chunks ----
__global__ void prep_weights(const float* __restrict__ W1, const float* __restrict__ W2,
                             const float* __restrict__ W3, const float* __restrict__ W4,
                             unsigned short* __restrict__ wt) {
  int i = blockIdx.x * 256 + threadIdx.x;
  if (i >= 22528) return;
  float v; int n, k, K, base;
  if (i < 4096)       { n = i >> 6, k = i & 63;  K = 64;  base = 0;     v = W1[k * 64 + n]; }
  else if (i < 12288) { int j = i - 4096;  n = j >> 6, k = j & 63;  K = 64;  base = 4096;  v = W2[k * 128 + n]; }
  else if (i < 20480) { int j = i - 12288; n = j >> 7, k = j & 127; K = 128; base = 12288; v = W3[k * 64 + n]; }
  else                { int j = i - 20480; n = j >> 6, k = j & 63;  K = 64;  base = 20480; v = W4[k * 32 + n]; }
  int o = base + n * K + ((((k >> 3) ^ (n & 7)) << 3) + (k & 7));
  wt[o] = f2bf(v);
}

// ---- CSR build ----
__global__ void hist_kernel(const int* __restrict__ ei, int* __restrict__ histI, int E) {
  int e = blockIdx.x * 256 + threadIdx.x;
  if (e < E) atomicAdd(&histI[ei[E + e]], 1);
}

// phase 1: per-block exclusive scan of 2048 elems (256 thr x 8), write block sums
__global__ void scan_blocks(const int* __restrict__ histI, int* __restrict__ row_start,
                            int* __restrict__ blockSums, int N) {
  __shared__ int wsum[4];
  const int lane = threadIdx.x & 63, w = threadIdx.x >> 6;
  const int i0 = blockIdx.x * 2048 + threadIdx.x * 8;
  int v[8];
#pragma unroll
  for (int j = 0; j < 8; ++j) { int i = i0 + j; v[j] = (i < N) ? histI[i] : 0; }
  int s = 0;
#pragma unroll
  for (int j = 0; j < 8; ++j) { int t = v[j]; v[j] = s; s += t; }  // thread-local exclusive
  int ss = s;
#pragma unroll
  for (int d = 1; d < 64; d <<= 1) { int t = __shfl_up(ss, d, 64); if (lane >= d) ss += t; }
  if (lane == 63) wsum[w] = ss;
  __syncthreads();
  int wOff = 0;
#pragma unroll
  for (int k = 0; k < 4; ++k) if (k < w) wOff += wsum[k];
  const int tOff = wOff + (ss - s);
#pragma unroll
  for (int j = 0; j < 8; ++j) { int i = i0 + j; if (i < N) row_start[i] = tOff + v[j]; }
  if (threadIdx.x == 255) blockSums[blockIdx.x] = wOff + ss;
}

// phase 2: single wave turns blockSums into exclusive offsets (nb <= 64)
__global__ void scan_tops(int* __restrict__ blockSums, int nb) {
  const int lane = threadIdx.x;
  int v = (lane < nb) ? blockSums[lane] : 0;
  int s = v;
#pragma unroll
  for (int d = 1; d < 64; d <<= 1) { int t = __shfl_up(s, d, 64); if (lane >= d) s += t; }
  if (lane < nb) blockSums[lane] = s - v;
}

// phase 3: add block offsets
__global__ void scan_add(int* __restrict__ row_start, const int* __restrict__ blockSums, int N) {
  int i = blockIdx.x * 256 + threadIdx.x;
  if (i < N) row_start[i] += blockSums[i >> 11];
}

__global__ void fill_kernel(const int* __restrict__ ei, const int* __restrict__ row_start,
                            int* __restrict__ wcnt, int2* __restrict__ edlist, int E) {
  int e = blockIdx.x * 256 + threadIdx.x;
  if (e >= E) return;
  int d = ei[E + e];
  int slot = atomicAdd(&wcnt[d], 1);
  edlist[row_start[d] + slot] = make_int2(e, d);
}

// ---- one MLP layer: dst = relu(W^T srcH + b); weights read from LDS ----
template <int MT, int KS, int SS, int DS>
__device__ __forceinline__ void mlp_layer(const unsigned char* src, unsigned char* dst,
                                          const unsigned char* wl, const float* biasL, int lane) {
  const int edge = lane & 15, g = lane >> 4;
  asm volatile("s_waitcnt lgkmcnt(0)" ::: "memory");
  u16x8 bfrag[KS];
#pragma unroll
  for (int ks = 0; ks < KS; ++ks)
    bfrag[ks] = *(const u16x8*)(src + aswz(edge, ks * 32 + g * 8, SS));
#pragma unroll
  for (int mt = 0; mt < MT; ++mt) {
    const int n = mt * 16 + edge;
    u16x8 af[KS];
#pragma unroll
    for (int ks = 0; ks < KS; ++ks)
      af[ks] = *(const u16x8*)(wl + n * (KS * 64) + (((ks * 4 + g) ^ (edge & 7)) << 4));
    const float4 bv = *(const float4*)(biasL + mt * 16 + g * 4);
    f32x4 acc = {bv.x, bv.y, bv.z, bv.w};
    __builtin_amdgcn_s_setprio(1);
#pragma unroll
    for (int ks = 0; ks < KS; ++ks)
      acc = __builtin_amdgcn_mfma_f32_16x16x32_bf16(
          __builtin_bit_cast(bf16x8, af[ks]), __builtin_bit_cast(bf16x8, bfrag[ks]),
          acc, 0, 0, 0);
    __builtin_amdgcn_s_setprio(0);
    const int fb = mt * 16 + g * 4;
    uint2 q;
    q.x = pack_bf2(fmaxf(acc[0], 0.f), fmaxf(acc[1], 0.f));
    q.y = pack_bf2(fmaxf(acc[2], 0.f), fmaxf(acc[3], 0.f));
    *(uint2*)(dst + aswz(edge, fb, DS)) = q;
  }
}

// prefetch one tile's gather (CSR order) into registers
__device__ __forceinline__ void load_tile(int ebase, int E, const int2* __restrict__ edlist,
                                          const float* __restrict__ x, const float* __restrict__ ea,
                                          int lane, float4& xa, float4& xb, float4& ya, float4& yb,
                                          int& dstA) {
  const int el = ebase + (lane >> 2);   // CSR position staged by this lane
  const int part = lane & 3;
  xa = make_float4(0.f, 0.f, 0.f, 0.f); xb = xa; ya = xa; yb = xa;
  if (el < E) {
    const int2 ed = edlist[el];
    const float4* xp = (const float4*)(x + (size_t)ed.y * 32 + part * 8);
    xa = xp[0]; xb = xp[1];
    const float4* ep = (const float4*)(ea + (size_t)ed.x * 32 + part * 8);
    ya = ep[0]; yb = ep[1];
  }
  const int pos = ebase + (lane & 15);
  dstA = (pos < E) ? edlist[pos].y : -1;
}

// LDS layout: [weights 45056][bias 1152][16 waves x (buf0 4096 + buf1 2048)]
#define BIAS_OFF   45056
#define ACT_OFF    46208

__global__ __launch_bounds__(1024, 4)
void gnn_main(const float* __restrict__ x, const int2* __restrict__ edlist,
              const float* __restrict__ ea, const unsigned short* __restrict__ wt,
              const float* __restrict__ b1, const float* __restrict__ b2,
              const float* __restrict__ b3, const float* __restrict__ b4,
              float* __restrict__ out, int E, int numTiles) {
  __shared__ __align__(16) unsigned char lds[ACT_OFF + 16 * 6144];
  {
    const u16x8* gw = (const u16x8*)wt;
    u16x8* lw = (u16x8*)lds;
    for (int i = threadIdx.x; i < 2816; i += 1024) lw[i] = gw[i];
    float* biasW = (float*)(lds + BIAS_OFF);
    for (int i = threadIdx.x; i < 288; i += 1024) {
      float v;
      if (i < 64) v = b1[i];
      else if (i < 192) v = b2[i - 64];
      else if (i < 256) v = b3[i - 192];
      else v = b4[i - 256];
      biasW[i] = v;
    }
  }
  __syncthreads();

  const int lane = threadIdx.x & 63, wid = threadIdx.x >> 6;
  const int edge = lane & 15, g = lane >> 4;
  const float* biasLds = (const float*)(lds + BIAS_OFF);
  unsigned char* buf0 = lds + ACT_OFF + wid * 6144;
  unsigned char* buf1 = buf0 + 4096;
  const unsigned char* wl1 = lds;
  const unsigned char* wl2 = lds + 8192;
  const unsigned char* wl3 = lds + 24576;
  const unsigned char* wl4 = lds + 40960;

  const int wgl = blockIdx.x * 16 + wid;
  const int wstride = gridDim.x * 16;

  float4 xa, xb, ya, yb; int dstA = -1;
  if (wgl < numTiles) load_tile(wgl * 16, E, edlist, x, ea, lane, xa, xb, ya, yb, dstA);

  for (int tile = wgl; tile < numTiles; tile += wstride) {
    // ---- stage current tile H0 = concat(x[dst], edge_attr) as bf16 [16][64] ----
    uint4 hx, he;
    hx.x = pack_bf2(xa.x, xa.y); hx.y = pack_bf2(xa.z, xa.w);
    hx.z = pack_bf2(xb.x, xb.y); hx.w = pack_bf2(xb.z, xb.w);
    he.x = pack_bf2(ya.x, ya.y); he.y = pack_bf2(ya.z, ya.w);
    he.z = pack_bf2(yb.x, yb.y); he.w = pack_bf2(yb.z, yb.w);
    const int e2 = lane >> 2, part = lane & 3;
    *(uint4*)(buf0 + aswz(e2, part * 8, 256)) = hx;
    *(uint4*)(buf0 + aswz(e2, 32 + part * 8, 256)) = he;

    const int curDst = dstA;

    // ---- issue next tile's gather now; it drains under the MFMA chain ----
    const int nt = tile + wstride;
    float4 nxa, nxb, nya, nyb; int ndst = -1;
    if (nt < numTiles) load_tile(nt * 16, E, edlist, x, ea, lane, nxa, nxb, nya, nyb, ndst);
    else { nxa = make_float4(0,0,0,0); nxb = nxa; nya = nxa; nyb = nxa; }

    mlp_layer<4, 2, 256, 128>(buf0, buf1, wl1, biasLds + 0,   lane);   // 64 -> 64
    mlp_layer<8, 2, 128, 256>(buf1, buf0, wl2, biasLds + 64,  lane);   // 64 -> 128
    mlp_layer<4, 4, 256, 128>(buf0, buf1, wl3, biasLds + 192, lane);   // 128 -> 64

    // ---- layer 4 + segmented lane-reduce + sparse atomics ----
    asm volatile("s_waitcnt lgkmcnt(0)" ::: "memory");
    u16x8 bf4[2];
#pragma unroll
    for (int ks = 0; ks < 2; ++ks)
      bf4[ks] = *(const u16x8*)(buf1 + aswz(edge, ks * 32 + g * 8, 128));
    float vals[8];
#pragma unroll
    for (int mt = 0; mt < 2; ++mt) {
      const int n = mt * 16 + edge;
      u16x8 af[2];
#pragma unroll
      for (int ks = 0; ks < 2; ++ks)
        af[ks] = *(const u16x8*)(wl4 + n * 128 + (((ks * 4 + g) ^ (edge & 7)) << 4));
      const float4 bv = *(const float4*)(biasLds + 256 + mt * 16 + g * 4);
      f32x4 acc = {bv.x, bv.y, bv.z, bv.w};
      __builtin_amdgcn_s_setprio(1);
#pragma unroll
      for (int ks = 0; ks < 2; ++ks)
        acc = __builtin_amdgcn_mfma_f32_16x16x32_bf16(
            __builtin_bit_cast(bf16x8, af[ks]), __builtin_bit_cast(bf16x8, bf4[ks]),
            acc, 0, 0, 0);
      __builtin_amdgcn_s_setprio(0);
#pragma unroll
      for (int r = 0; r < 4; ++r) vals[mt * 4 + r] = fmaxf(acc[r], 0.f);
    }

    // segmented sum across the 16-edge lane dim (CSR order => equal dsts adjacent)
    const int li = edge;
    const int prev = __shfl_up(curDst, 1, 16);
    const bool is_head = (li == 0) || (prev != curDst);
    const unsigned long long hb = __ballot(is_head);
    const unsigned gm = (unsigned)((hb >> (g * 16)) & 0xFFFFu);
    const unsigned below = gm & ((1u << li) | ((1u << li) - 1u));
    const int dist = li - (31 - __clz(below));
#pragma unroll
    for (int d = 1; d < 16; d <<= 1) {
#pragma unroll
      for (int t = 0; t < 8; ++t) {
        const float tv = __shfl_up(vals[t], d, 16);
        if (dist >= d) vals[t] += tv;
      }
    }
    const bool is_end = (li == 15) || ((gm >> (li + 1)) & 1u);
    if (is_end && curDst >= 0) {
      float* op = out + (size_t)curDst * 32 + g * 4;
#pragma unroll
      for (int t = 0; t < 4; ++t) unsafeAtomicAdd(op + t, vals[t]);
#pragma unroll
      for (int t = 0; t < 4; ++t) unsafeAtomicAdd(op + 16 + t, vals[4 + t]);
    }

    xa = nxa; xb = nxb; ya = nya; yb = nyb; dstA = ndst;
  }
}

__global__ void div_kernel(float* __restrict__ out, const int* __restrict__ histI, int total) {
  int i = blockIdx.x * 256 + threadIdx.x;
  if (i < total) out[i] = out[i] / fmaxf((float)histI[i >> 5], 1.0f);
}

extern "C" void kernel_launch(void* const* d_in, const int* in_sizes, int n_in,
                              void* d_out, int out_size, void* d_ws, size_t ws_size,
                              hipStream_t stream) {
  const float* x  = (const float*)d_in[0];
  const int*   ei = (const int*)d_in[1];
  const float* ea = (const float*)d_in[2];
  const float* W1 = (const float*)d_in[3];
  const float* b1 = (const float*)d_in[4];
  const float* W2 = (const float*)d_in[5];
  const float* b2 = (const float*)d_in[6];
  const float* W3 = (const float*)d_in[7];
  const float* b3 = (const float*)d_in[8];
  const float* W4 = (const float*)d_in[9];
  const float* b4 = (const float*)d_in[10];
  const int N = in_sizes[0] / 32;
  const int E = in_sizes[1] / 2;
  float* out = (float*)d_out;

  char* ws = (char*)d_ws;
  size_t off = 0;
  auto alloc = [&](size_t bytes) { size_t o = off; off += (bytes + 255) & ~(size_t)255; return o; };
  int* histI      = (int*)(ws + alloc((size_t)N * 4));
  int* wcnt       = (int*)(ws + alloc((size_t)N * 4));
  int* row_start  = (int*)(ws + alloc((size_t)(N + 1) * 4));
  int* blockSums  = (int*)(ws + alloc(64 * 4));
  int2* edlist    = (int2*)(ws + alloc((size_t)E * 8));
  unsigned short* wt = (unsigned short*)(ws + alloc(22528 * 2));

  hipMemsetAsync(d_out, 0, (size_t)out_size * sizeof(float), stream);
  hipMemsetAsync(histI, 0, (size_t)N * 4, stream);
  hipMemsetAsync(wcnt, 0, (size_t)N * 4, stream);

  prep_weights<<<(22528 + 255) / 256, 256, 0, stream>>>(W1, W2, W3, W4, wt);
  hist_kernel<<<(E + 255) / 256, 256, 0, stream>>>(ei, histI, E);
  const int nb = (N + 2047) / 2048;
  scan_blocks<<<nb, 256, 0, stream>>>(histI, row_start, blockSums, N);
  scan_tops<<<1, 64, 0, stream>>>(blockSums, nb);
  scan_add<<<(N + 255) / 256, 256, 0, stream>>>(row_start, blockSums, N);
  fill_kernel<<<(E + 255) / 256, 256, 0, stream>>>(ei, row_start, wcnt, edlist, E);

  const int numTiles = (E + 15) / 16;
  gnn_main<<<256, 1024, 0, stream>>>(x, edlist, ea, wt, b1, b2, b3, b4, out, E, numTiles);
  const int total = N * 32;
  div_kernel<<<(total + 255) / 256, 256, 0, stream>>>(out, histI, total);
}